// Round 8
// baseline (335.822 us; speedup 1.0000x reference)
//
#include <hip/hip_runtime.h>

// GCN 2-layer forward on MI355X (gfx950).
// out = A @ relu(A @ (x@W1) + b1) @ W2 + b2   (A = weighted edge aggregation)
// R8: agg1+gemm2 fused (16 nodes/block; h -> LDS -> one MFMA by wave 0 -> S2;
//     H never touches global). CSR slimmed (no sbase array). 8 dispatches.

#define F0 512
#define F1 128
#define F2 40
#define F2P 48   // padded S2 row (bf16)

typedef short bf16x8 __attribute__((ext_vector_type(8)));
typedef float f32x4 __attribute__((ext_vector_type(4)));

// accurate RNE bf16 (weights, once per call)
static __device__ __forceinline__ unsigned short f2b(float f){
    union { float f; unsigned int u; } x; x.f = f;
    unsigned int u = x.u;
    unsigned int r = (u + 0x7fffu + ((u >> 16) & 1u)) >> 16;
    return (unsigned short)r;
}
// fast round-half-up bf16 (activations)
static __device__ __forceinline__ unsigned short f2b_fast(float f){
    return (unsigned short)((__float_as_uint(f) + 0x8000u) >> 16);
}
static __device__ __forceinline__ unsigned int pack2(float a, float b){
    unsigned int ua = __float_as_uint(a) + 0x8000u;
    unsigned int ub = __float_as_uint(b) + 0x8000u;
    return __builtin_amdgcn_perm(ub, ua, 0x07060302u);
}
static __device__ __forceinline__ bf16x8 pack8(float4 v0, float4 v1){
    union { bf16x8 v; unsigned int d[4]; } r;
    r.d[0] = pack2(v0.x, v0.y);
    r.d[1] = pack2(v0.z, v0.w);
    r.d[2] = pack2(v1.x, v1.y);
    r.d[3] = pack2(v1.z, v1.w);
    return r.v;
}
static __device__ __forceinline__ float b2f(unsigned short h){
    union { unsigned int u; float f; } x; x.u = ((unsigned int)h) << 16; return x.f;
}
// fp16 pack/unpack for edge weights (w in [0,1): rel err 2^-11)
static __device__ __forceinline__ unsigned short f2h(float f){
    union { _Float16 h; unsigned short u; } x; x.h = (_Float16)f; return x.u;
}
static __device__ __forceinline__ float h2f(unsigned short u){
    union { unsigned short u; _Float16 h; } x; x.u = u; return (float)x.h;
}

// ---------------- weight prep + cnt8 zero (fused) ----------------
__global__ void prep_w(const float* __restrict__ W1, const float* __restrict__ W2,
                       unsigned short* __restrict__ W1t, unsigned short* __restrict__ W2t,
                       int* __restrict__ cnt8, int n8){
    int idx = blockIdx.x*256 + threadIdx.x;
    if (idx < n8) cnt8[idx] = 0;
    if (idx < F0*F1){                    // W1 [512][128] -> W1t [128][512]
        int k = idx >> 7, n = idx & 127;
        W1t[(size_t)n*F0 + k] = f2b(W1[idx]);
    } else if (idx < F0*F1 + F2P*F1){    // W2 [128][40] -> W2t [48][128]
        int j = idx - F0*F1;
        int n = j >> 7, k = j & 127;
        float v = (n < F2) ? W2[(size_t)k*F2 + n] : 0.f;
        W2t[j] = f2b(v);
    }
}

// ---------------- CSR build: sharded hist (8 shards/node) ----------------
__global__ void hist_kernel(const int* __restrict__ dst, int* __restrict__ cnt8,
                            unsigned short* __restrict__ slot, int E){
    int e = blockIdx.x*256 + threadIdx.x;
    if (e < E){
        int d = dst[e];
        int s = e & 7;
        slot[e] = (unsigned short)atomicAdd(&cnt8[d*8 + s], 1);
    }
}

// per-1024-node chunk scan; emits per-node shard local prefixes
__global__ void scan1_kernel(const int* __restrict__ cnt8, int* __restrict__ offs,
                             unsigned short* __restrict__ lsp, int* __restrict__ bsum, int n){
    __shared__ int sd[256];
    int tid = threadIdx.x;
    int base = blockIdx.x*1024 + tid*4;
    int t[4];
    #pragma unroll
    for (int j=0;j<4;j++){
        int node = base+j;
        int tot = 0;
        if (node < n){
            int4 c0 = *(const int4*)&cnt8[(size_t)node*8];
            int4 c1 = *(const int4*)&cnt8[(size_t)node*8+4];
            unsigned short lp1,lp2,lp3,lp4,lp5,lp6,lp7;
            int run = c0.x; lp1=(unsigned short)run;
            run += c0.y; lp2=(unsigned short)run;
            run += c0.z; lp3=(unsigned short)run;
            run += c0.w; lp4=(unsigned short)run;
            run += c1.x; lp5=(unsigned short)run;
            run += c1.y; lp6=(unsigned short)run;
            run += c1.z; lp7=(unsigned short)run;
            run += c1.w; tot = run;
            ushort4 a, b;
            a.x=0;   a.y=lp1; a.z=lp2; a.w=lp3;
            b.x=lp4; b.y=lp5; b.z=lp6; b.w=lp7;
            *(ushort4*)&lsp[(size_t)node*8]   = a;
            *(ushort4*)&lsp[(size_t)node*8+4] = b;
        }
        t[j] = tot;
    }
    int v1=t[0], v2=t[0]+t[1], v3=v2+t[2];
    int s = v3+t[3];
    sd[tid]=s; __syncthreads();
    for (int off=1; off<256; off<<=1){
        int tt = (tid>=off)? sd[tid-off] : 0;
        __syncthreads();
        sd[tid] += tt;
        __syncthreads();
    }
    int excl = sd[tid] - s;
    if (base+0<n) offs[base+0]=excl;
    if (base+1<n) offs[base+1]=excl+v1;
    if (base+2<n) offs[base+2]=excl+v2;
    if (base+3<n) offs[base+3]=excl+v3;
    if (tid==255) bsum[blockIdx.x]=sd[255];
}

// block-sum prefix fused; finalizes offs only (no sbase materialization)
__global__ void scan3_kernel(int* __restrict__ offs, const int* __restrict__ bsum,
                             int n, int E, int nb){
    __shared__ int sexcl;
    int tid = threadIdx.x;
    if (tid < 64){
        int v = (tid < nb) ? bsum[tid] : 0;
        int orig = v;
        #pragma unroll
        for (int off=1; off<64; off<<=1){
            int t = __shfl_up(v, off);
            if (tid >= off) v += t;
        }
        int g = blockIdx.x >> 2;
        if (tid == g) sexcl = v - orig;
    }
    __syncthreads();
    int i = blockIdx.x*256 + tid;
    if (i<n) offs[i] += sexcl;
    if (i==0) offs[n]=E;
}

// atomic-free scatter: pos = offs[d] + lsp[d][shard] + slot[e]
__global__ void scatter_kernel(const int* __restrict__ src, const int* __restrict__ dst,
                               const float* __restrict__ w,
                               const int* __restrict__ offs,
                               const unsigned short* __restrict__ lsp,
                               const unsigned short* __restrict__ slot,
                               unsigned int* __restrict__ edges, int E){
    int e = blockIdx.x*256+threadIdx.x;
    if (e<E){
        int d = dst[e];
        int pos = offs[d] + (int)lsp[d*8 + (e & 7)] + (int)slot[e];
        edges[pos] = ((unsigned int)src[e] << 16) | (unsigned int)f2h(w[e]);
    }
}

// ---- GEMM1: X[M,512]fp32 @ W1t -> S1 bf16 [M,128] (unchanged from R7) ----
__global__ __launch_bounds__(256) void gemm1_mfma(const float* __restrict__ X,
                                                  const unsigned short* __restrict__ W1t,
                                                  unsigned short* __restrict__ S1, int M){
    __shared__ unsigned short sB[128*136];
    int tid = threadIdx.x;
    int wave = tid >> 6, lane = tid & 63;
    int quad = lane >> 4, l16 = lane & 15;
    int row0 = blockIdx.x * 64;
    int myrow = row0 + wave*16 + l16;
    int arow = min(myrow, M-1);
    const float* xrow = X + (size_t)arow * F0;

    f32x4 acc[8];
    #pragma unroll
    for (int c=0;c<8;c++) acc[c] = (f32x4){0.f,0.f,0.f,0.f};

    float4 aq[4][2];
    #pragma unroll
    for (int s=0;s<4;s++){
        aq[s][0] = *(const float4*)(xrow + s*32 + quad*8);
        aq[s][1] = *(const float4*)(xrow + s*32 + quad*8 + 4);
    }

    for (int p = 0; p < 4; p++){
        __syncthreads();
        #pragma unroll
        for (int i=0;i<8;i++){
            int idx = tid + i*256;
            int nn = idx >> 4, c8 = idx & 15;
            *(float4*)&sB[nn*136 + c8*8] =
                *(const float4*)&W1t[(size_t)nn*F0 + p*128 + c8*8];
        }
        __syncthreads();
        float4 nq[4][2];
        if (p < 3){
            const float* nx = xrow + (p+1)*128;
            #pragma unroll
            for (int s=0;s<4;s++){
                nq[s][0] = *(const float4*)(nx + s*32 + quad*8);
                nq[s][1] = *(const float4*)(nx + s*32 + quad*8 + 4);
            }
        }
        #pragma unroll
        for (int s=0;s<4;s++){
            bf16x8 af = pack8(aq[s][0], aq[s][1]);
            #pragma unroll
            for (int c=0;c<8;c++){
                bf16x8 b = *(bf16x8*)&sB[(c*16 + l16)*136 + s*32 + quad*8];
                acc[c] = __builtin_amdgcn_mfma_f32_16x16x32_bf16(af, b, acc[c], 0, 0, 0);
            }
        }
        if (p < 3){
            #pragma unroll
            for (int s=0;s<4;s++){ aq[s][0]=nq[s][0]; aq[s][1]=nq[s][1]; }
        }
    }
    #pragma unroll
    for (int c=0;c<8;c++){
        #pragma unroll
        for (int r=0;r<4;r++){
            int grow = row0 + wave*16 + quad*4 + r;
            if (grow < M) S1[(size_t)grow*F1 + c*16 + l16] = f2b_fast(acc[c][r]);
        }
    }
}

// ---- agg1+gemm2 fused: S2 = (relu(A@S1 + b1)) @ W2, 16 nodes/block ----
// 4 waves x 4 sequential nodes each; h -> LDS (bf16, stride 136); wave 0 runs
// the 16x16x32 MFMA (K=128 via 4 steps) against W2t and stores S2 rows.
__global__ __launch_bounds__(256) void agg1_gemm2(const unsigned short* __restrict__ S1,
                                                  const int* __restrict__ offs,
                                                  const unsigned int* __restrict__ edges,
                                                  const float* __restrict__ b1,
                                                  const unsigned short* __restrict__ W2t,
                                                  unsigned short* __restrict__ S2, int n){
    __shared__ unsigned short hT[16*136];   // 16 h-rows, padded stride (2-way alias, free)
    int tid = threadIdx.x;
    int wave = tid >> 6, lane = tid & 63;
    int half = lane >> 5, fl = lane & 31;
    int nodeBase = blockIdx.x * 16;

    float4 bb;
    if (lane < 32) bb = *(const float4*)&b1[fl*4];

    #pragma unroll
    for (int j=0;j<4;j++){
        int ln = wave*4 + j;
        int node = nodeBase + ln;
        double a0=0.0, a1=0.0, a2=0.0, a3=0.0;
        if (node < n){
            int e0 = offs[node], e1 = offs[node+1];
            int e = e0;
            for (; e+8 <= e1; e += 8){
                unsigned int rA = edges[e   + half];
                unsigned int rB = edges[e+2 + half];
                unsigned int rC = edges[e+4 + half];
                unsigned int rD = edges[e+6 + half];
                ushort4 vA = *(const ushort4*)&S1[((size_t)(rA>>16))*F1 + fl*4];
                ushort4 vB = *(const ushort4*)&S1[((size_t)(rB>>16))*F1 + fl*4];
                ushort4 vC = *(const ushort4*)&S1[((size_t)(rC>>16))*F1 + fl*4];
                ushort4 vD = *(const ushort4*)&S1[((size_t)(rD>>16))*F1 + fl*4];
                double wA = h2f((unsigned short)rA), wB = h2f((unsigned short)rB);
                double wC = h2f((unsigned short)rC), wD = h2f((unsigned short)rD);
                a0 += wA*b2f(vA.x) + wB*b2f(vB.x) + wC*b2f(vC.x) + wD*b2f(vD.x);
                a1 += wA*b2f(vA.y) + wB*b2f(vB.y) + wC*b2f(vC.y) + wD*b2f(vD.y);
                a2 += wA*b2f(vA.z) + wB*b2f(vB.z) + wC*b2f(vC.z) + wD*b2f(vD.z);
                a3 += wA*b2f(vA.w) + wB*b2f(vB.w) + wC*b2f(vC.w) + wD*b2f(vD.w);
            }
            for (; e < e1; e += 2){
                int ee = e + half;
                if (ee < e1){
                    unsigned int r = edges[ee];
                    ushort4 v = *(const ushort4*)&S1[((size_t)(r>>16))*F1 + fl*4];
                    double w = h2f((unsigned short)r);
                    a0 += w*b2f(v.x); a1 += w*b2f(v.y); a2 += w*b2f(v.z); a3 += w*b2f(v.w);
                }
            }
        }
        a0 += __shfl_down(a0, 32);
        a1 += __shfl_down(a1, 32);
        a2 += __shfl_down(a2, 32);
        a3 += __shfl_down(a3, 32);
        if (lane < 32){
            float o0 = (float)(a0 + (double)bb.x);
            float o1 = (float)(a1 + (double)bb.y);
            float o2 = (float)(a2 + (double)bb.z);
            float o3 = (float)(a3 + (double)bb.w);
            o0 = o0>0.f?o0:0.f; o1 = o1>0.f?o1:0.f;
            o2 = o2>0.f?o2:0.f; o3 = o3>0.f?o3:0.f;
            union { ushort4 v; unsigned int d[2]; } o;
            o.d[0] = pack2(o0, o1);
            o.d[1] = pack2(o2, o3);
            *(ushort4*)&hT[ln*136 + fl*4] = o.v;
        }
    }
    __syncthreads();
    // wave 0: S2[16 nodes][48] = hT @ W2t^T   (MFMA 16x16x32, K=128)
    if (wave == 0){
        int quad = lane >> 4, l16 = lane & 15;
        f32x4 acc[3];
        #pragma unroll
        for (int c=0;c<3;c++) acc[c] = (f32x4){0.f,0.f,0.f,0.f};
        #pragma unroll
        for (int ks=0; ks<4; ks++){
            bf16x8 a = *(const bf16x8*)&hT[l16*136 + ks*32 + quad*8];
            #pragma unroll
            for (int c=0;c<3;c++){
                bf16x8 b = *(const bf16x8*)&W2t[(size_t)(c*16 + l16)*F1 + ks*32 + quad*8];
                acc[c] = __builtin_amdgcn_mfma_f32_16x16x32_bf16(a, b, acc[c], 0, 0, 0);
            }
        }
        #pragma unroll
        for (int c=0;c<3;c++){
            #pragma unroll
            for (int r=0;r<4;r++){
                int grow = nodeBase + quad*4 + r;
                if (grow < n) S2[(size_t)grow*F2P + c*16 + l16] = f2b_fast(acc[c][r]);
            }
        }
    }
}

// ---- agg2: out = A@S2 + b2, F=40 (unchanged) ----
__global__ void agg2_kernel(const unsigned short* __restrict__ S2, const int* __restrict__ offs,
                            const unsigned int* __restrict__ edges,
                            const float* __restrict__ b2, float* __restrict__ out, int n){
    int node = blockIdx.x*4 + (threadIdx.x >> 6);  // one wave per node
    int lane = threadIdx.x & 63;
    if (node >= n) return;
    int grp = lane >> 4, gl = lane & 15;
    bool act = gl < 10;
    int e0 = offs[node], e1 = offs[node+1];
    double a0=0.0, a1=0.0, a2=0.0, a3=0.0;
    for (int e = e0; e < e1; e += 4){
        int ee = e + grp;
        if (ee < e1 && act){
            unsigned int r = edges[ee];
            ushort4 v = *(const ushort4*)&S2[((size_t)(r>>16))*F2P + gl*4];
            double w = h2f((unsigned short)r);
            a0 += w*b2f(v.x); a1 += w*b2f(v.y); a2 += w*b2f(v.z); a3 += w*b2f(v.w);
        }
    }
    a0 += __shfl_down(a0, 32); a0 += __shfl_down(a0, 16);
    a1 += __shfl_down(a1, 32); a1 += __shfl_down(a1, 16);
    a2 += __shfl_down(a2, 32); a2 += __shfl_down(a2, 16);
    a3 += __shfl_down(a3, 32); a3 += __shfl_down(a3, 16);
    if (lane < 10){
        float4 bb = *(const float4*)&b2[lane*4];
        float4 o;
        o.x = (float)(a0 + (double)bb.x);
        o.y = (float)(a1 + (double)bb.y);
        o.z = (float)(a2 + (double)bb.z);
        o.w = (float)(a3 + (double)bb.w);
        *(float4*)&out[(size_t)node*F2 + lane*4] = o;
    }
}

extern "C" void kernel_launch(void* const* d_in, const int* in_sizes, int n_in,
                              void* d_out, int out_size, void* d_ws, size_t ws_size,
                              hipStream_t stream){
    const float* x    = (const float*)d_in[0];
    const int*   esrc = (const int*)d_in[1];
    const int*   edst = (const int*)d_in[2];
    const float* ew   = (const float*)d_in[3];
    const float* W1   = (const float*)d_in[4];
    const float* b1   = (const float*)d_in[5];
    const float* W2   = (const float*)d_in[6];
    const float* b2   = (const float*)d_in[7];
    float* out = (float*)d_out;
    int N = in_sizes[0] / F0;   // 50000
    int E = in_sizes[1];        // 800000

    char* ws = (char*)d_ws;
    size_t off = 0;
    auto alloc = [&](size_t bytes)->void*{
        void* p = ws + off; off += (bytes + 255) & ~(size_t)255; return p;
    };
    unsigned short* S1 = (unsigned short*)alloc(sizeof(unsigned short)*(size_t)N*F1);  // 12.8 MB
    unsigned short* S2 = (unsigned short*)alloc(sizeof(unsigned short)*(size_t)N*F2P); // 4.8 MB
    unsigned short* W1t = (unsigned short*)alloc(sizeof(unsigned short)*F1*F0);
    unsigned short* W2t = (unsigned short*)alloc(sizeof(unsigned short)*F2P*F1);
    int*   offs  = (int*)alloc(sizeof(int)*(size_t)(N+1));
    int*   cnt8  = (int*)alloc(sizeof(int)*(size_t)N*8);                 // 1.6 MB
    unsigned short* lsp  = (unsigned short*)alloc(sizeof(unsigned short)*(size_t)N*8); // 0.8 MB
    unsigned short* slot = (unsigned short*)alloc(sizeof(unsigned short)*(size_t)E);   // 1.6 MB
    unsigned int* edges = (unsigned int*)alloc(sizeof(unsigned int)*(size_t)E);        // 3.2 MB
    int*   bsum  = (int*)alloc(sizeof(int)*64);

    int n8 = N*8;
    int prep_items = n8 > (F0*F1 + F2P*F1) ? n8 : (F0*F1 + F2P*F1);
    prep_w<<<(prep_items+255)/256,256,0,stream>>>(W1, W2, W1t, W2t, cnt8, n8);

    // CSR build: sharded hist -> scans -> atomic-free scatter
    hist_kernel<<<(E+255)/256,256,0,stream>>>(edst, cnt8, slot, E);
    int nb = (N+1023)/1024;     // 49 <= 64
    scan1_kernel<<<nb,256,0,stream>>>(cnt8, offs, lsp, bsum, N);
    scan3_kernel<<<(N+255)/256,256,0,stream>>>(offs, bsum, N, E, nb);
    scatter_kernel<<<(E+255)/256,256,0,stream>>>(esrc, edst, ew, offs, lsp, slot, edges, E);

    // layer 1 GEMM
    gemm1_mfma<<<(N+63)/64,256,0,stream>>>(x, W1t, S1, N);
    // layer 1 aggregation + layer 2 GEMM (fused)
    agg1_gemm2<<<(N+15)/16,256,0,stream>>>(S1, offs, edges, b1, W2t, S2, N);
    // layer 2 aggregation
    agg2_kernel<<<(N+3)/4,256,0,stream>>>(S2, offs, edges, b2, out, N);
}